// Round 3
// baseline (444.612 us; speedup 1.0000x reference)
//
#include <hip/hip_runtime.h>

// KernelizedHeadAttention, B=4 S=1024 D=2048 H=16 DH=128 DHID=128 DKER=64
// out[s] = [ sum_t (m? score+eps : exp(saw)) * v[t] ] / (rowsum_s + eps + exp(lse_s))
// R3: DRAM-locality fix. Column-slab reads of saw (64B granules, 4KB stride) capped
// HBM at ~800 GB/s. New streaming pre-pass writes P~ = m? -1 : exp(saw) (bf16, mask
// in sign bit) in [bh][tt][s][64] tiles -> attn phase reads are contiguous 8KB.
// vT also tiled [bh][tt][128][64] (contiguous 16KB/phase). Legacy path kept as
// fallback if ws_size is too small for the 134MB P~ buffer.

typedef __bf16 bf16_t;
typedef __attribute__((ext_vector_type(8))) __bf16 bf16x8;
typedef __attribute__((ext_vector_type(4))) float f32x4;

#define MFMA(a, b, c) __builtin_amdgcn_mfma_f32_16x16x32_bf16((a), (b), (c), 0, 0, 0)

static __device__ __forceinline__ float gelu_exact(float x) {
    return 0.5f * x * (1.0f + erff(x * 0.70710678118654752f));
}

// ---------------- weights: convert f32 -> bf16, transposed for B-fragments ----------------
__global__ __launch_bounds__(256) void conv_weights_kernel(
    const float* __restrict__ wq1, const float* __restrict__ wk1,
    const float* __restrict__ wq2, const float* __restrict__ wk2,
    const float* __restrict__ iK,
    bf16_t* __restrict__ wq1t, bf16_t* __restrict__ wk1t,
    bf16_t* __restrict__ wq2t, bf16_t* __restrict__ wk2t,
    bf16_t* __restrict__ iKt)
{
    const int idx = blockIdx.x * 256 + threadIdx.x;
    if (idx < 16 * 128 * 128) {           // [h][e][d] <- [h][d][e]
        int h = idx >> 14, e = (idx >> 7) & 127, d = idx & 127;
        wq1t[idx] = (bf16_t)wq1[(h << 14) + (d << 7) + e];
        wk1t[idx] = (bf16_t)wk1[(h << 14) + (d << 7) + e];
    }
    if (idx < 16 * 64 * 128) {            // [h][f][e] <- [h][e][f]
        int h = idx >> 13, f = (idx >> 7) & 63, e = idx & 127;
        wq2t[idx] = (bf16_t)wq2[(h << 13) + (e << 6) + f];
        wk2t[idx] = (bf16_t)wk2[(h << 13) + (e << 6) + f];
    }
    if (idx < 16 * 64 * 64) {             // [h][g][f] <- [h][f][g]
        int h = idx >> 12, g = (idx >> 6) & 63, f = idx & 63;
        iKt[idx] = (bf16_t)iK[(h << 12) + (f << 6) + g];
    }
}

// ---------------- V: [B,S,H,128] f32 -> vT tiled [B,H,tt(16),128,64] bf16 ---------------
__global__ __launch_bounds__(256) void conv_v_kernel(
    const float* __restrict__ v, bf16_t* __restrict__ vT)
{
    __shared__ bf16_t tr[128][72];
    const int bh = blockIdx.x, b = bh >> 4, h = bh & 15;
    const int tt = blockIdx.y;                  // t-tile index 0..15
    const int t0 = tt * 64;
    const int tid = threadIdx.x;
#pragma unroll
    for (int i = 0; i < 8; ++i) {
        int f4 = tid + 256 * i;                 // 2048 float4 = 64 t x 128 d
        int t = f4 >> 5, c4 = f4 & 31;
        const float4 vv = *reinterpret_cast<const float4*>(
            &v[((size_t)b * 1024 + t0 + t) * 2048 + h * 128 + c4 * 4]);
        tr[c4 * 4 + 0][t] = (bf16_t)vv.x;
        tr[c4 * 4 + 1][t] = (bf16_t)vv.y;
        tr[c4 * 4 + 2][t] = (bf16_t)vv.z;
        tr[c4 * 4 + 3][t] = (bf16_t)vv.w;
    }
    __syncthreads();
#pragma unroll
    for (int i = 0; i < 32; ++i) {
        int e = tid + 256 * i;                  // 8192 bf16
        int d = e >> 6, tl = e & 63;
        vT[(((size_t)bh * 16 + tt) * 128 + d) * 64 + tl] = tr[d][tl];
    }
}

// ---------------- P~ pre-pass: pt[bh][tt][s][64] = m ? -1 : exp(saw) (bf16) -------------
__global__ __launch_bounds__(256) void expmask_kernel(
    const float* __restrict__ saw, const unsigned char* __restrict__ mask8,
    bf16_t* __restrict__ pt)
{
    const int tid = threadIdx.x;
    const int w = tid >> 6, l = tid & 63;
    const int bh = blockIdx.x, b = bh >> 4;
    const int s0 = blockIdx.y * 64;

    __shared__ int mflag;
    if (tid == 0) {   // detect mask storage width: int32 => bytes 4i+1 all zero
        unsigned a = 0;
        for (int i = 0; i < 64; ++i) a |= mask8[4 * i + 1];
        mflag = (a == 0) ? 1 : 0;
    }
    __syncthreads();
    const bool mask_is_int = (mflag != 0);
    const int* mask32 = (const int*)mask8;

    const size_t sawb = ((size_t)bh << 20) + (size_t)s0 * 1024;
    const size_t mb = ((size_t)b << 20) + (size_t)s0 * 1024;

    for (int tc = 0; tc < 4; ++tc) {
#pragma unroll
        for (int i = 0; i < 16; ++i) {
            const int r = i * 4 + w;                 // row within 64-row chunk
            const int col = tc * 256 + l * 4;        // 1KB contiguous per wave-instr
            const size_t e = (size_t)r * 1024 + col;
            const float4 sv = *reinterpret_cast<const float4*>(&saw[sawb + e]);
            int m0, m1, m2, m3;
            if (mask_is_int) {
                const int4 mv = *reinterpret_cast<const int4*>(&mask32[mb + e]);
                m0 = mv.x; m1 = mv.y; m2 = mv.z; m3 = mv.w;
            } else {
                const uchar4 mv = *reinterpret_cast<const uchar4*>(&mask8[mb + e]);
                m0 = mv.x; m1 = mv.y; m2 = mv.z; m3 = mv.w;
            }
            bf16_t o[4];
            o[0] = m0 ? (bf16_t)(-1.0f) : (bf16_t)__expf(sv.x);
            o[1] = m1 ? (bf16_t)(-1.0f) : (bf16_t)__expf(sv.y);
            o[2] = m2 ? (bf16_t)(-1.0f) : (bf16_t)__expf(sv.z);
            o[3] = m3 ? (bf16_t)(-1.0f) : (bf16_t)__expf(sv.w);
            const int ttg = tc * 4 + (l >> 4);
            const int tin = (l & 15) * 4;            // 16 lanes x 8B = 128B contiguous
            *reinterpret_cast<uint2*>(
                &pt[(((size_t)bh * 16 + ttg) * 1024 + s0 + r) * 64 + tin]) =
                *reinterpret_cast<const uint2*>(o);
        }
    }
}

// ---------------- feature maps: qf = |gelu(gelu(q W1) W2)|, kf path w/ interaction ------
__global__ __launch_bounds__(256) void feat_kernel(
    const float* __restrict__ q, const float* __restrict__ k,
    const bf16_t* __restrict__ wq1t, const bf16_t* __restrict__ wq2t,
    const bf16_t* __restrict__ wk1t, const bf16_t* __restrict__ wk2t,
    const bf16_t* __restrict__ iKt,
    const float* __restrict__ sD, const float* __restrict__ sD2,
    bf16_t* __restrict__ qf, bf16_t* __restrict__ kf)
{
    __shared__ bf16_t xa[64][136];
    __shared__ bf16_t h1[64][136];
    __shared__ bf16_t k2[64][72];

    const int tid = threadIdx.x;
    const int lane = tid & 63, w = tid >> 6;
    const int lr = lane & 15, lg = lane >> 4;
    const int row0 = blockIdx.x * 64;          // token rows over B*S=4096
    const int h = blockIdx.y;
    const int path = blockIdx.z;               // 0 = q, 1 = k

    const float* X = path ? k : q;
    const bf16_t* w1t = path ? wk1t : wq1t;
    const bf16_t* w2t = path ? wk2t : wq2t;
    bf16_t* outp = path ? kf : qf;

#pragma unroll
    for (int i = 0; i < 8; ++i) {              // stage X tile [64][128] -> LDS bf16
        int f4 = tid + 256 * i;
        int r = f4 >> 5, c4 = f4 & 31;
        const float4 vv = *reinterpret_cast<const float4*>(
            &X[(size_t)(row0 + r) * 2048 + h * 128 + c4 * 4]);
        xa[r][c4 * 4 + 0] = (bf16_t)vv.x;
        xa[r][c4 * 4 + 1] = (bf16_t)vv.y;
        xa[r][c4 * 4 + 2] = (bf16_t)vv.z;
        xa[r][c4 * 4 + 3] = (bf16_t)vv.w;
    }
    __syncthreads();

    // stage 1: [64x128] @ W1[128x128] -> gelu -> h1
    bf16x8 a1[4];
#pragma unroll
    for (int kk = 0; kk < 4; ++kk)
        a1[kk] = *reinterpret_cast<const bf16x8*>(&xa[w * 16 + lr][kk * 32 + lg * 8]);
#pragma unroll
    for (int nt = 0; nt < 8; ++nt) {
        f32x4 acc = {0.f, 0.f, 0.f, 0.f};
#pragma unroll
        for (int kk = 0; kk < 4; ++kk) {
            bf16x8 bfr = *reinterpret_cast<const bf16x8*>(
                &w1t[(size_t)h * 16384 + (nt * 16 + lr) * 128 + kk * 32 + lg * 8]);
            acc = MFMA(a1[kk], bfr, acc);
        }
#pragma unroll
        for (int r = 0; r < 4; ++r)
            h1[w * 16 + lg * 4 + r][nt * 16 + lr] = (bf16_t)gelu_exact(acc[r]);
    }
    __syncthreads();

    // stage 2: [64x128] @ W2[128x64]
    bf16x8 a2[4];
#pragma unroll
    for (int kk = 0; kk < 4; ++kk)
        a2[kk] = *reinterpret_cast<const bf16x8*>(&h1[w * 16 + lr][kk * 32 + lg * 8]);

    if (path == 0) {
#pragma unroll
        for (int nt = 0; nt < 4; ++nt) {
            f32x4 acc = {0.f, 0.f, 0.f, 0.f};
#pragma unroll
            for (int kk = 0; kk < 4; ++kk) {
                bf16x8 bfr = *reinterpret_cast<const bf16x8*>(
                    &w2t[(size_t)h * 8192 + (nt * 16 + lr) * 128 + kk * 32 + lg * 8]);
                acc = MFMA(a2[kk], bfr, acc);
            }
#pragma unroll
            for (int r = 0; r < 4; ++r) {
                int n = row0 + w * 16 + lg * 4 + r;
                int bb = n >> 10, s = n & 1023;
                outp[(((size_t)bb * 16 + h) * 1024 + s) * 64 + nt * 16 + lr] =
                    (bf16_t)fabsf(gelu_exact(acc[r]));
            }
        }
    } else {
#pragma unroll
        for (int nt = 0; nt < 4; ++nt) {
            f32x4 acc = {0.f, 0.f, 0.f, 0.f};
#pragma unroll
            for (int kk = 0; kk < 4; ++kk) {
                bf16x8 bfr = *reinterpret_cast<const bf16x8*>(
                    &w2t[(size_t)h * 8192 + (nt * 16 + lr) * 128 + kk * 32 + lg * 8]);
                acc = MFMA(a2[kk], bfr, acc);
            }
#pragma unroll
            for (int r = 0; r < 4; ++r) {
                int f = nt * 16 + lr;
                k2[w * 16 + lg * 4 + r][f] =
                    (bf16_t)(fabsf(sD[h * 64 + f]) * gelu_exact(acc[r]));
            }
        }
        __syncthreads();
        // stage 3: kf = |kf2 + (kf2 @ interK) * sD2|
        bf16x8 a3[2];
#pragma unroll
        for (int kk = 0; kk < 2; ++kk)
            a3[kk] = *reinterpret_cast<const bf16x8*>(&k2[w * 16 + lr][kk * 32 + lg * 8]);
#pragma unroll
        for (int nt = 0; nt < 4; ++nt) {
            f32x4 acc = {0.f, 0.f, 0.f, 0.f};
#pragma unroll
            for (int kk = 0; kk < 2; ++kk) {
                bf16x8 bfr = *reinterpret_cast<const bf16x8*>(
                    &iKt[(size_t)h * 4096 + (nt * 16 + lr) * 64 + kk * 32 + lg * 8]);
                acc = MFMA(a3[kk], bfr, acc);
            }
#pragma unroll
            for (int r = 0; r < 4; ++r) {
                int row = w * 16 + lg * 4 + r;
                int g = nt * 16 + lr;
                float base = (float)k2[row][g];
                float kv = fabsf(base + acc[r] * sD2[h * 64 + g]);
                int n = row0 + row;
                int bb = n >> 10, s = n & 1023;
                outp[(((size_t)bb * 16 + h) * 1024 + s) * 64 + g] = (bf16_t)kv;
            }
        }
    }
}

// ---------------- fused attention (P~ path): contiguous-tile reads only -----------------
// Per t-tile phase; P~ exp-part prefetched one tile ahead (ushort regs). Mask is P~<0.
#define PTILE(T0, CUR, NXT, TTN)                                                 \
  {                                                                              \
    f32x4 c[4];                                                                  \
    _Pragma("unroll")                                                            \
    for (int nt = 0; nt < 4; ++nt) {                                             \
      f32x4 acc = fzero;                                                         \
      const size_t kb = ((size_t)bh * 1024 + (T0) + nt * 16 + lr) * 64;          \
      bf16x8 kb0 = *reinterpret_cast<const bf16x8*>(&kf[kb + lg * 8]);           \
      bf16x8 kb1 = *reinterpret_cast<const bf16x8*>(&kf[kb + 32 + lg * 8]);      \
      acc = MFMA(aq0, kb0, acc);                                                 \
      acc = MFMA(aq1, kb1, acc);                                                 \
      c[nt] = acc;                                                               \
    }                                                                            \
    /* issue next tile's P~ loads now; consumed one full phase later */          \
    _Pragma("unroll")                                                            \
    for (int nt = 0; nt < 4; ++nt) {                                             \
      _Pragma("unroll")                                                          \
      for (int r = 0; r < 4; ++r)                                                \
        NXT[nt * 4 + r] = ptp[(size_t)(TTN) * 65536 + r * 64 + nt * 16];         \
    }                                                                            \
    _Pragma("unroll")                                                            \
    for (int nt = 0; nt < 4; ++nt) {                                             \
      _Pragma("unroll")                                                          \
      for (int r = 0; r < 4; ++r) {                                              \
        float pe = __uint_as_float((unsigned)CUR[nt * 4 + r] << 16);             \
        float sc = c[nt][r];                                                     \
        bool msk = pe < 0.f;                                                     \
        float wv = msk ? (sc + 1e-6f) : pe;                                      \
        rowsum[r] += msk ? sc : 0.f;                                             \
        p[w * 16 + lg * 4 + r][nt * 16 + lr] = (bf16_t)wv;                       \
      }                                                                          \
    }                                                                            \
    asm volatile("s_waitcnt lgkmcnt(0)" ::: "memory");                           \
    __builtin_amdgcn_sched_barrier(0);                                           \
    bf16x8 ap0 = *reinterpret_cast<const bf16x8*>(&p[w * 16 + lr][lg * 8]);      \
    bf16x8 ap1 = *reinterpret_cast<const bf16x8*>(&p[w * 16 + lr][32 + lg * 8]); \
    _Pragma("unroll")                                                            \
    for (int dt = 0; dt < 8; ++dt) {                                             \
      const size_t vb = (((size_t)bh * 16 + ((T0) >> 6)) * 128 + dt * 16 + lr) * 64; \
      bf16x8 vb0 = *reinterpret_cast<const bf16x8*>(&vT[vb + lg * 8]);           \
      bf16x8 vb1 = *reinterpret_cast<const bf16x8*>(&vT[vb + 32 + lg * 8]);      \
      oacc[dt] = MFMA(ap0, vb0, oacc[dt]);                                       \
      oacc[dt] = MFMA(ap1, vb1, oacc[dt]);                                       \
    }                                                                            \
  }

__global__ __launch_bounds__(256) void attn_pt_kernel(
    const bf16_t* __restrict__ qf, const bf16_t* __restrict__ kf,
    const bf16_t* __restrict__ vT, const bf16_t* __restrict__ pt,
    const float* __restrict__ lse, float* __restrict__ out)
{
    __shared__ bf16_t p[64][72];

    const int tid = threadIdx.x;
    const int lane = tid & 63, w = tid >> 6;
    const int lr = lane & 15, lg = lane >> 4;
    const int s0 = blockIdx.x * 64;
    const int bh = blockIdx.y;
    const int b = bh >> 4, h = bh & 15;

    bf16x8 aq0, aq1;
    {
        const size_t qb = ((size_t)bh * 1024 + s0 + w * 16 + lr) * 64;
        aq0 = *reinterpret_cast<const bf16x8*>(&qf[qb + lg * 8]);
        aq1 = *reinterpret_cast<const bf16x8*>(&qf[qb + 32 + lg * 8]);
    }

    const f32x4 fzero = {0.f, 0.f, 0.f, 0.f};
    f32x4 oacc[8];
#pragma unroll
    for (int i = 0; i < 8; ++i) oacc[i] = fzero;
    float rowsum[4] = {0.f, 0.f, 0.f, 0.f};

    const int lrow = s0 + w * 16 + lg * 4;      // this lane's first s-row
    const int lcol = lr;
    // per-lane base into pt tiles: element (tt, r, nt) at ptp[tt*65536 + r*64 + nt*16]
    const unsigned short* ptp = (const unsigned short*)pt
        + ((size_t)bh * 16) * 65536 + (size_t)lrow * 64 + lcol;

    unsigned short sA[16], sB[16];
#pragma unroll
    for (int nt = 0; nt < 4; ++nt)              // prologue: tile 0 -> A
#pragma unroll
        for (int r = 0; r < 4; ++r)
            sA[nt * 4 + r] = ptp[r * 64 + nt * 16];

    for (int tt8 = 0; tt8 < 8; ++tt8) {
        const int t0 = tt8 * 128;
        PTILE(t0,      sA, sB, (tt8 * 2 + 1));
        PTILE(t0 + 64, sB, sA, ((tt8 * 2 + 2) & 15));   // wrap keeps last load in-bounds
    }

#pragma unroll
    for (int r = 0; r < 4; ++r) {
        float s = rowsum[r];
#pragma unroll
        for (int m = 1; m < 16; m <<= 1) s += __shfl_xor(s, m);
        rowsum[r] = s;
    }
    float invden[4];
#pragma unroll
    for (int r = 0; r < 4; ++r) {
        const int srow = s0 + w * 16 + lg * 4 + r;
        invden[r] = 1.0f / (rowsum[r] + 1e-6f + __expf(lse[(size_t)bh * 1024 + srow]));
    }
#pragma unroll
    for (int dt = 0; dt < 8; ++dt) {
#pragma unroll
        for (int r = 0; r < 4; ++r) {
            const int srow = s0 + w * 16 + lg * 4 + r;
            out[((size_t)b * 1024 + srow) * 2048 + h * 128 + dt * 16 + lr] =
                oacc[dt][r] * invden[r];
        }
    }
}

// ---------------- legacy attention (no P~ buffer; used if ws too small) -----------------
#define LTILE(T0, CUR, NXT, TNEXT)                                               \
  {                                                                              \
    f32x4 c[4];                                                                  \
    _Pragma("unroll")                                                            \
    for (int nt = 0; nt < 4; ++nt) {                                             \
      f32x4 acc = fzero;                                                         \
      const size_t kb = ((size_t)bh * 1024 + (T0) + nt * 16 + lr) * 64;          \
      bf16x8 kb0 = *reinterpret_cast<const bf16x8*>(&kf[kb + lg * 8]);           \
      bf16x8 kb1 = *reinterpret_cast<const bf16x8*>(&kf[kb + 32 + lg * 8]);      \
      acc = MFMA(aq0, kb0, acc);                                                 \
      acc = MFMA(aq1, kb1, acc);                                                 \
      c[nt] = acc;                                                               \
    }                                                                            \
    _Pragma("unroll")                                                            \
    for (int nt = 0; nt < 4; ++nt) {                                             \
      _Pragma("unroll")                                                          \
      for (int r = 0; r < 4; ++r)                                                \
        NXT[nt * 4 + r] = sawp[(size_t)r * 1024 + nt * 16 + (TNEXT)];            \
    }                                                                            \
    _Pragma("unroll")                                                            \
    for (int nt = 0; nt < 4; ++nt) {                                             \
      _Pragma("unroll")                                                          \
      for (int r = 0; r < 4; ++r) {                                              \
        const size_t e = (size_t)(lrow + r) * 1024 + (T0) + nt * 16 + lcol;      \
        unsigned mv = mask_is_int ? (unsigned)mask32[mb + e]                     \
                                  : (unsigned)mask8[mb + e];                     \
        float sc = c[nt][r];                                                     \
        float wv = mv ? (sc + 1e-6f) : __expf(CUR[nt * 4 + r]);                  \
        rowsum[r] += mv ? sc : 0.f;                                              \
        p[w * 16 + lg * 4 + r][nt * 16 + lr] = (bf16_t)wv;                       \
      }                                                                          \
    }                                                                            \
    asm volatile("s_waitcnt lgkmcnt(0)" ::: "memory");                           \
    __builtin_amdgcn_sched_barrier(0);                                           \
    bf16x8 ap0 = *reinterpret_cast<const bf16x8*>(&p[w * 16 + lr][lg * 8]);      \
    bf16x8 ap1 = *reinterpret_cast<const bf16x8*>(&p[w * 16 + lr][32 + lg * 8]); \
    _Pragma("unroll")                                                            \
    for (int dt = 0; dt < 8; ++dt) {                                             \
      const size_t vb = (((size_t)bh * 16 + ((T0) >> 6)) * 128 + dt * 16 + lr) * 64; \
      bf16x8 vb0 = *reinterpret_cast<const bf16x8*>(&vT[vb + lg * 8]);           \
      bf16x8 vb1 = *reinterpret_cast<const bf16x8*>(&vT[vb + 32 + lg * 8]);      \
      oacc[dt] = MFMA(ap0, vb0, oacc[dt]);                                       \
      oacc[dt] = MFMA(ap1, vb1, oacc[dt]);                                       \
    }                                                                            \
  }

__global__ __launch_bounds__(256) void attn_legacy_kernel(
    const bf16_t* __restrict__ qf, const bf16_t* __restrict__ kf,
    const bf16_t* __restrict__ vT,
    const unsigned char* __restrict__ mask8,
    const float* __restrict__ saw, const float* __restrict__ lse,
    float* __restrict__ out)
{
    __shared__ bf16_t p[64][72];
    __shared__ int mflag;

    const int tid = threadIdx.x;
    const int lane = tid & 63, w = tid >> 6;
    const int lr = lane & 15, lg = lane >> 4;
    const int s0 = blockIdx.x * 64;
    const int bh = blockIdx.y;
    const int b = bh >> 4, h = bh & 15;

    if (tid == 0) {
        unsigned a = 0;
        for (int i = 0; i < 64; ++i) a |= mask8[4 * i + 1];
        mflag = (a == 0) ? 1 : 0;
    }
    __syncthreads();
    const bool mask_is_int = (mflag != 0);
    const int* mask32 = (const int*)mask8;

    bf16x8 aq0, aq1;
    {
        const size_t qb = ((size_t)bh * 1024 + s0 + w * 16 + lr) * 64;
        aq0 = *reinterpret_cast<const bf16x8*>(&qf[qb + lg * 8]);
        aq1 = *reinterpret_cast<const bf16x8*>(&qf[qb + 32 + lg * 8]);
    }

    const f32x4 fzero = {0.f, 0.f, 0.f, 0.f};
    f32x4 oacc[8];
#pragma unroll
    for (int i = 0; i < 8; ++i) oacc[i] = fzero;
    float rowsum[4] = {0.f, 0.f, 0.f, 0.f};

    const size_t sawb = (size_t)bh << 20;
    const size_t mb = (size_t)b << 20;
    const int lrow = s0 + w * 16 + lg * 4;
    const int lcol = lr;
    const float* sawp = &saw[sawb + (size_t)lrow * 1024 + lcol];

    float sA[16], sB[16];
#pragma unroll
    for (int nt = 0; nt < 4; ++nt)
#pragma unroll
        for (int r = 0; r < 4; ++r)
            sA[nt * 4 + r] = sawp[(size_t)r * 1024 + nt * 16];

    for (int tt = 0; tt < 8; ++tt) {
        const int t0 = tt * 128;
        LTILE(t0,      sA, sB, t0 + 64);
        LTILE(t0 + 64, sB, sA, (t0 + 128) & 1023);
    }

#pragma unroll
    for (int r = 0; r < 4; ++r) {
        float s = rowsum[r];
#pragma unroll
        for (int m = 1; m < 16; m <<= 1) s += __shfl_xor(s, m);
        rowsum[r] = s;
    }
    float invden[4];
#pragma unroll
    for (int r = 0; r < 4; ++r) {
        const int srow = s0 + w * 16 + lg * 4 + r;
        invden[r] = 1.0f / (rowsum[r] + 1e-6f + __expf(lse[(size_t)bh * 1024 + srow]));
    }
#pragma unroll
    for (int dt = 0; dt < 8; ++dt) {
#pragma unroll
        for (int r = 0; r < 4; ++r) {
            const int srow = s0 + w * 16 + lg * 4 + r;
            out[((size_t)b * 1024 + srow) * 2048 + h * 128 + dt * 16 + lr] =
                oacc[dt][r] * invden[r];
        }
    }
}

extern "C" void kernel_launch(void* const* d_in, const int* in_sizes, int n_in,
                              void* d_out, int out_size, void* d_ws, size_t ws_size,
                              hipStream_t stream)
{
    const float* q   = (const float*)d_in[0];
    const float* k   = (const float*)d_in[1];
    const float* v   = (const float*)d_in[2];
    const unsigned char* mask = (const unsigned char*)d_in[3];
    const float* lse = (const float*)d_in[4];
    const float* saw = (const float*)d_in[5];
    const float* wq1 = (const float*)d_in[6];
    const float* wk1 = (const float*)d_in[7];
    const float* wq2 = (const float*)d_in[8];
    const float* wk2 = (const float*)d_in[9];
    const float* iK  = (const float*)d_in[10];
    const float* sD  = (const float*)d_in[11];
    const float* sD2 = (const float*)d_in[12];
    float* out = (float*)d_out;

    bf16_t* wsb  = (bf16_t*)d_ws;
    bf16_t* wq1t = wsb;                    // 16*128*128 = 262144
    bf16_t* wk1t = wq1t + 262144;
    bf16_t* wq2t = wk1t + 262144;          // 16*64*128 = 131072
    bf16_t* wk2t = wq2t + 131072;
    bf16_t* iKt  = wk2t + 131072;          // 16*64*64  = 65536
    bf16_t* qf   = iKt  + 65536;           // 4*16*1024*64 = 4194304
    bf16_t* kf   = qf   + 4194304;
    bf16_t* vT   = kf   + 4194304;         // 4*16*128*1024 = 8388608 (tiled)
    bf16_t* pt   = vT   + 8388608;         // 64*1024*1024 = 67108864 (134MB)
    const size_t need_bytes = (size_t)(17629184 + 67108864) * 2;   // ~169.5 MB

    conv_weights_kernel<<<dim3(1024), dim3(256), 0, stream>>>(
        wq1, wk1, wq2, wk2, iK, wq1t, wk1t, wq2t, wk2t, iKt);
    conv_v_kernel<<<dim3(64, 16), dim3(256), 0, stream>>>(v, vT);
    feat_kernel<<<dim3(64, 16, 2), dim3(256), 0, stream>>>(
        q, k, wq1t, wq2t, wk1t, wk2t, iKt, sD, sD2, qf, kf);

    if (ws_size >= need_bytes) {
        expmask_kernel<<<dim3(64, 16), dim3(256), 0, stream>>>(saw, mask, pt);
        attn_pt_kernel<<<dim3(16, 64), dim3(256), 0, stream>>>(
            qf, kf, vT, pt, lse, out);
    } else {
        attn_legacy_kernel<<<dim3(16, 64), dim3(256), 0, stream>>>(
            qf, kf, vT, mask, saw, lse, out);
    }
}

// Round 4
// 230.271 us; speedup vs baseline: 1.9308x; 1.9308x over previous
//
#include <hip/hip_runtime.h>

// KernelizedHeadAttention, B=4 S=1024 D=2048 H=16 DH=128 DHID=128 DKER=64
// out[s] = [ sum_t (m? score+eps : exp(saw)) * v[t] ] / (rowsum_s + eps + exp(lse_s))
// R4: single fused attention kernel with 2-phase async LDS pipeline:
//   - saw+mask reg-staged -> exp+mask -> ebuf (bf16) dbuf, written one phase ahead
//   - vT staged via global_load_lds into XOR-swizzled LDS dbuf (conflict-free b128 reads)
//   - kf direct per-wave (L1/L2-hot), P through LDS, one __syncthreads per phase
//   - XCD-aware block swizzle: all 16 s-blocks of a bh on one XCD's L2

typedef __bf16 bf16_t;
typedef __attribute__((ext_vector_type(8))) __bf16 bf16x8;
typedef __attribute__((ext_vector_type(4))) float f32x4;

#define MFMA(a, b, c) __builtin_amdgcn_mfma_f32_16x16x32_bf16((a), (b), (c), 0, 0, 0)

typedef __attribute__((address_space(3))) void as3_void;
typedef __attribute__((address_space(1))) const void as1_void;
static __device__ __forceinline__ void gload16(const void* g, void* l) {
    __builtin_amdgcn_global_load_lds((as1_void*)g, (as3_void*)l, 16, 0, 0);
}

static __device__ __forceinline__ float gelu_exact(float x) {
    return 0.5f * x * (1.0f + erff(x * 0.70710678118654752f));
}

// ---------------- weights: convert f32 -> bf16, transposed for B-fragments ----------------
__global__ __launch_bounds__(256) void conv_weights_kernel(
    const float* __restrict__ wq1, const float* __restrict__ wk1,
    const float* __restrict__ wq2, const float* __restrict__ wk2,
    const float* __restrict__ iK,
    bf16_t* __restrict__ wq1t, bf16_t* __restrict__ wk1t,
    bf16_t* __restrict__ wq2t, bf16_t* __restrict__ wk2t,
    bf16_t* __restrict__ iKt)
{
    const int idx = blockIdx.x * 256 + threadIdx.x;
    if (idx < 16 * 128 * 128) {           // [h][e][d] <- [h][d][e]
        int h = idx >> 14, e = (idx >> 7) & 127, d = idx & 127;
        wq1t[idx] = (bf16_t)wq1[(h << 14) + (d << 7) + e];
        wk1t[idx] = (bf16_t)wk1[(h << 14) + (d << 7) + e];
    }
    if (idx < 16 * 64 * 128) {            // [h][f][e] <- [h][e][f]
        int h = idx >> 13, f = (idx >> 7) & 63, e = idx & 127;
        wq2t[idx] = (bf16_t)wq2[(h << 13) + (e << 6) + f];
        wk2t[idx] = (bf16_t)wk2[(h << 13) + (e << 6) + f];
    }
    if (idx < 16 * 64 * 64) {             // [h][g][f] <- [h][f][g]
        int h = idx >> 12, g = (idx >> 6) & 63, f = idx & 63;
        iKt[idx] = (bf16_t)iK[(h << 12) + (f << 6) + g];
    }
}

// ---------------- V: [B,S,H,128] f32 -> vT tiled [B,H,tt(16),128,64] bf16 ---------------
__global__ __launch_bounds__(256) void conv_v_kernel(
    const float* __restrict__ v, bf16_t* __restrict__ vT)
{
    __shared__ bf16_t tr[128][72];
    const int bh = blockIdx.x, b = bh >> 4, h = bh & 15;
    const int tt = blockIdx.y;
    const int t0 = tt * 64;
    const int tid = threadIdx.x;
#pragma unroll
    for (int i = 0; i < 8; ++i) {
        int f4 = tid + 256 * i;                 // 2048 float4 = 64 t x 128 d
        int t = f4 >> 5, c4 = f4 & 31;
        const float4 vv = *reinterpret_cast<const float4*>(
            &v[((size_t)b * 1024 + t0 + t) * 2048 + h * 128 + c4 * 4]);
        tr[c4 * 4 + 0][t] = (bf16_t)vv.x;
        tr[c4 * 4 + 1][t] = (bf16_t)vv.y;
        tr[c4 * 4 + 2][t] = (bf16_t)vv.z;
        tr[c4 * 4 + 3][t] = (bf16_t)vv.w;
    }
    __syncthreads();
#pragma unroll
    for (int i = 0; i < 32; ++i) {
        int e = tid + 256 * i;                  // 8192 bf16
        int d = e >> 6, tl = e & 63;
        vT[(((size_t)bh * 16 + tt) * 128 + d) * 64 + tl] = tr[d][tl];
    }
}

// ---------------- feature maps: qf = |gelu(gelu(q W1) W2)|, kf path w/ interaction ------
__global__ __launch_bounds__(256) void feat_kernel(
    const float* __restrict__ q, const float* __restrict__ k,
    const bf16_t* __restrict__ wq1t, const bf16_t* __restrict__ wq2t,
    const bf16_t* __restrict__ wk1t, const bf16_t* __restrict__ wk2t,
    const bf16_t* __restrict__ iKt,
    const float* __restrict__ sD, const float* __restrict__ sD2,
    bf16_t* __restrict__ qf, bf16_t* __restrict__ kf)
{
    __shared__ bf16_t xa[64][136];
    __shared__ bf16_t h1[64][136];
    __shared__ bf16_t k2[64][72];

    const int tid = threadIdx.x;
    const int lane = tid & 63, w = tid >> 6;
    const int lr = lane & 15, lg = lane >> 4;
    const int row0 = blockIdx.x * 64;
    const int h = blockIdx.y;
    const int path = blockIdx.z;               // 0 = q, 1 = k

    const float* X = path ? k : q;
    const bf16_t* w1t = path ? wk1t : wq1t;
    const bf16_t* w2t = path ? wk2t : wq2t;
    bf16_t* outp = path ? kf : qf;

#pragma unroll
    for (int i = 0; i < 8; ++i) {
        int f4 = tid + 256 * i;
        int r = f4 >> 5, c4 = f4 & 31;
        const float4 vv = *reinterpret_cast<const float4*>(
            &X[(size_t)(row0 + r) * 2048 + h * 128 + c4 * 4]);
        xa[r][c4 * 4 + 0] = (bf16_t)vv.x;
        xa[r][c4 * 4 + 1] = (bf16_t)vv.y;
        xa[r][c4 * 4 + 2] = (bf16_t)vv.z;
        xa[r][c4 * 4 + 3] = (bf16_t)vv.w;
    }
    __syncthreads();

    bf16x8 a1[4];
#pragma unroll
    for (int kk = 0; kk < 4; ++kk)
        a1[kk] = *reinterpret_cast<const bf16x8*>(&xa[w * 16 + lr][kk * 32 + lg * 8]);
#pragma unroll
    for (int nt = 0; nt < 8; ++nt) {
        f32x4 acc = {0.f, 0.f, 0.f, 0.f};
#pragma unroll
        for (int kk = 0; kk < 4; ++kk) {
            bf16x8 bfr = *reinterpret_cast<const bf16x8*>(
                &w1t[(size_t)h * 16384 + (nt * 16 + lr) * 128 + kk * 32 + lg * 8]);
            acc = MFMA(a1[kk], bfr, acc);
        }
#pragma unroll
        for (int r = 0; r < 4; ++r)
            h1[w * 16 + lg * 4 + r][nt * 16 + lr] = (bf16_t)gelu_exact(acc[r]);
    }
    __syncthreads();

    bf16x8 a2[4];
#pragma unroll
    for (int kk = 0; kk < 4; ++kk)
        a2[kk] = *reinterpret_cast<const bf16x8*>(&h1[w * 16 + lr][kk * 32 + lg * 8]);

    if (path == 0) {
#pragma unroll
        for (int nt = 0; nt < 4; ++nt) {
            f32x4 acc = {0.f, 0.f, 0.f, 0.f};
#pragma unroll
            for (int kk = 0; kk < 4; ++kk) {
                bf16x8 bfr = *reinterpret_cast<const bf16x8*>(
                    &w2t[(size_t)h * 8192 + (nt * 16 + lr) * 128 + kk * 32 + lg * 8]);
                acc = MFMA(a2[kk], bfr, acc);
            }
#pragma unroll
            for (int r = 0; r < 4; ++r) {
                int n = row0 + w * 16 + lg * 4 + r;
                int bb = n >> 10, s = n & 1023;
                outp[(((size_t)bb * 16 + h) * 1024 + s) * 64 + nt * 16 + lr] =
                    (bf16_t)fabsf(gelu_exact(acc[r]));
            }
        }
    } else {
#pragma unroll
        for (int nt = 0; nt < 4; ++nt) {
            f32x4 acc = {0.f, 0.f, 0.f, 0.f};
#pragma unroll
            for (int kk = 0; kk < 4; ++kk) {
                bf16x8 bfr = *reinterpret_cast<const bf16x8*>(
                    &w2t[(size_t)h * 8192 + (nt * 16 + lr) * 128 + kk * 32 + lg * 8]);
                acc = MFMA(a2[kk], bfr, acc);
            }
#pragma unroll
            for (int r = 0; r < 4; ++r) {
                int f = nt * 16 + lr;
                k2[w * 16 + lg * 4 + r][f] =
                    (bf16_t)(fabsf(sD[h * 64 + f]) * gelu_exact(acc[r]));
            }
        }
        __syncthreads();
        bf16x8 a3[2];
#pragma unroll
        for (int kk = 0; kk < 2; ++kk)
            a3[kk] = *reinterpret_cast<const bf16x8*>(&k2[w * 16 + lr][kk * 32 + lg * 8]);
#pragma unroll
        for (int nt = 0; nt < 4; ++nt) {
            f32x4 acc = {0.f, 0.f, 0.f, 0.f};
#pragma unroll
            for (int kk = 0; kk < 2; ++kk) {
                bf16x8 bfr = *reinterpret_cast<const bf16x8*>(
                    &iKt[(size_t)h * 4096 + (nt * 16 + lr) * 64 + kk * 32 + lg * 8]);
                acc = MFMA(a3[kk], bfr, acc);
            }
#pragma unroll
            for (int r = 0; r < 4; ++r) {
                int row = w * 16 + lg * 4 + r;
                int g = nt * 16 + lr;
                float base = (float)k2[row][g];
                float kv = fabsf(base + acc[r] * sD2[h * 64 + g]);
                int n = row0 + row;
                int bb = n >> 10, s = n & 1023;
                outp[(((size_t)bb * 16 + h) * 1024 + s) * 64 + g] = (bf16_t)kv;
            }
        }
    }
}

// ---------------- fused attention: 2-phase async pipeline -------------------------------
__global__ __launch_bounds__(256, 2) void attn_fused_kernel(
    const bf16_t* __restrict__ qf, const bf16_t* __restrict__ kf,
    const bf16_t* __restrict__ vT,
    const unsigned char* __restrict__ mask8,
    const float* __restrict__ saw, const float* __restrict__ lse,
    float* __restrict__ out)
{
    __shared__ bf16_t vbuf[2][128 * 64];    // XOR-swizzled V tiles (16KB each)
    __shared__ bf16_t ebuf[2][64 * 64];     // m? -1 : exp(saw) tiles (8KB each)
    __shared__ bf16_t p[64][72];            // P staging (9.2KB)
    __shared__ int mflag;

    const int tid = threadIdx.x;
    const int lane = tid & 63, w = tid >> 6;
    const int lr = lane & 15, lg = lane >> 4;

    // XCD swizzle: linear id di -> (xcd = di&7); all 16 s-blocks of a bh share one XCD
    const int di = blockIdx.y * 16 + blockIdx.x;   // 0..1023
    const int xcd = di & 7, rr = di >> 3;
    const int bh = xcd + 8 * (rr >> 4);
    const int s0 = (rr & 15) * 64;
    const int b = bh >> 4, h = bh & 15;

    if (tid == 0) {   // detect mask storage width: int32 => bytes 4i+1 all zero
        unsigned a = 0;
        for (int i = 0; i < 64; ++i) a |= mask8[4 * i + 1];
        mflag = (a == 0) ? 1 : 0;
    }
    __syncthreads();
    const bool mask_is_int = (mflag != 0);
    const int* mask32 = (const int*)mask8;

    // staging-thread mapping: thread handles (row strow, 16 t-cols at stcg*16)
    const int strow = tid >> 2;
    const int stcg = tid & 3;
    const size_t saw_base = ((size_t)bh << 20) + (size_t)(s0 + strow) * 1024 + stcg * 16;
    const size_t m_base   = ((size_t)b << 20) + (size_t)(s0 + strow) * 1024 + stcg * 16;

    // vT staging mapping (inverse-swizzled global source, linear LDS dest)
    const int vrow = tid >> 3;                     // 0..31 (+32 per round)
    const int vcol8 = (tid & 7) ^ (vrow & 7);
    const bf16_t* vt_bh = vT + (size_t)bh * 131072;

    bf16x8 aq0, aq1;
    {
        const size_t qb = ((size_t)bh * 1024 + s0 + w * 16 + lr) * 64;
        aq0 = *reinterpret_cast<const bf16x8*>(&qf[qb + lg * 8]);
        aq1 = *reinterpret_cast<const bf16x8*>(&qf[qb + 32 + lg * 8]);
    }

    const f32x4 fzero = {0.f, 0.f, 0.f, 0.f};
    f32x4 oacc[8];
#pragma unroll
    for (int i = 0; i < 8; ++i) oacc[i] = fzero;
    float rowsum[4] = {0.f, 0.f, 0.f, 0.f};

#define STAGE_VT(BUF, TILE)                                                      \
    {                                                                            \
        const bf16_t* vg = vt_bh + (size_t)(TILE) * 8192 + vcol8 * 8;            \
        char* lb = (char*)&vbuf[BUF][0] + w * 1024;                              \
        _Pragma("unroll")                                                        \
        for (int j = 0; j < 4; ++j)                                              \
            gload16(vg + (size_t)(32 * j + vrow) * 64, lb + j * 4096);           \
    }

    float4 s4[4];
    int4 mi4[4];
    uint4 mu;

#define LOAD_SAWM(TILE)                                                          \
    {                                                                            \
        _Pragma("unroll")                                                        \
        for (int j = 0; j < 4; ++j)                                              \
            s4[j] = *reinterpret_cast<const float4*>(                            \
                &saw[saw_base + (size_t)(TILE) * 64 + j * 4]);                   \
        if (mask_is_int) {                                                       \
            _Pragma("unroll")                                                    \
            for (int j = 0; j < 4; ++j)                                          \
                mi4[j] = *reinterpret_cast<const int4*>(                         \
                    &mask32[m_base + (size_t)(TILE) * 64 + j * 4]);              \
        } else {                                                                 \
            mu = *reinterpret_cast<const uint4*>(                                \
                &mask8[m_base + (size_t)(TILE) * 64]);                           \
        }                                                                        \
    }

#define WRITE_EBUF(BUF)                                                          \
    {                                                                            \
        float srr[16] = {s4[0].x, s4[0].y, s4[0].z, s4[0].w,                     \
                         s4[1].x, s4[1].y, s4[1].z, s4[1].w,                     \
                         s4[2].x, s4[2].y, s4[2].z, s4[2].w,                     \
                         s4[3].x, s4[3].y, s4[3].z, s4[3].w};                    \
        int mrr[16];                                                             \
        if (mask_is_int) {                                                       \
            int t0_[16] = {mi4[0].x, mi4[0].y, mi4[0].z, mi4[0].w,               \
                           mi4[1].x, mi4[1].y, mi4[1].z, mi4[1].w,               \
                           mi4[2].x, mi4[2].y, mi4[2].z, mi4[2].w,               \
                           mi4[3].x, mi4[3].y, mi4[3].z, mi4[3].w};              \
            _Pragma("unroll")                                                    \
            for (int j = 0; j < 16; ++j) mrr[j] = t0_[j];                        \
        } else {                                                                 \
            unsigned ua[4] = {mu.x, mu.y, mu.z, mu.w};                           \
            _Pragma("unroll")                                                    \
            for (int j = 0; j < 16; ++j)                                         \
                mrr[j] = (int)((ua[j >> 2] >> (8 * (j & 3))) & 255u);            \
        }                                                                        \
        bf16x8 e0, e1;                                                           \
        _Pragma("unroll")                                                        \
        for (int j = 0; j < 8; ++j)                                              \
            e0[j] = mrr[j] ? (bf16_t)(-1.0f) : (bf16_t)__expf(srr[j]);           \
        _Pragma("unroll")                                                        \
        for (int j = 0; j < 8; ++j)                                              \
            e1[j] = mrr[8 + j] ? (bf16_t)(-1.0f) : (bf16_t)__expf(srr[8 + j]);   \
        *reinterpret_cast<bf16x8*>(&ebuf[BUF][strow * 64 + stcg * 16]) = e0;     \
        *reinterpret_cast<bf16x8*>(&ebuf[BUF][strow * 64 + stcg * 16 + 8]) = e1; \
    }

    // ---- prologue: stage tile 0 into buffer 0
    STAGE_VT(0, 0);
    LOAD_SAWM(0);
    WRITE_EBUF(0);
    __syncthreads();          // drains vmcnt (gload_lds) + lgkm (ds_write)

    int cur = 0;
    const int xorv = (lr & 7) << 4;

    for (int i = 0; i < 16; ++i) {
        const int nxt = cur ^ 1;
        const int tnext = (i + 1) & 15;
        // A: issue async staging for next tile
        STAGE_VT(nxt, tnext);
        // B: issue saw+mask loads for next tile (consumed at H)
        LOAD_SAWM(tnext);
        // C: QK^T for this wave's 16 rows x 64 t-cols (kf direct, L1/L2-hot)
        f32x4 c[4];
        {
            const int t0 = i * 64;
#pragma unroll
            for (int nt = 0; nt < 4; ++nt) {
                f32x4 acc = fzero;
                const size_t kb = ((size_t)bh * 1024 + t0 + nt * 16 + lr) * 64;
                bf16x8 kb0 = *reinterpret_cast<const bf16x8*>(&kf[kb + lg * 8]);
                bf16x8 kb1 = *reinterpret_cast<const bf16x8*>(&kf[kb + 32 + lg * 8]);
                acc = MFMA(aq0, kb0, acc);
                acc = MFMA(aq1, kb1, acc);
                c[nt] = acc;
            }
        }
        // D: elementwise merge using ebuf[cur]
#pragma unroll
        for (int nt = 0; nt < 4; ++nt) {
#pragma unroll
            for (int r = 0; r < 4; ++r) {
                float pe = (float)ebuf[cur][(w * 16 + lg * 4 + r) * 64 + nt * 16 + lr];
                float sc = c[nt][r];
                bool msk = pe < 0.f;
                float wv = msk ? (sc + 1e-6f) : pe;
                rowsum[r] += msk ? sc : 0.f;
                p[w * 16 + lg * 4 + r][nt * 16 + lr] = (bf16_t)wv;
            }
        }
        // E: PV from swizzled vbuf[cur] (P rows are wave-private; compiler tracks lgkm)
        {
            bf16x8 ap0 = *reinterpret_cast<const bf16x8*>(&p[w * 16 + lr][lg * 8]);
            bf16x8 ap1 = *reinterpret_cast<const bf16x8*>(&p[w * 16 + lr][32 + lg * 8]);
            const char* vb = (const char*)&vbuf[cur][0];
#pragma unroll
            for (int dt = 0; dt < 8; ++dt) {
                const int row = dt * 16 + lr;
                bf16x8 v0 = *reinterpret_cast<const bf16x8*>(
                    vb + row * 128 + ((lg * 16) ^ xorv));
                bf16x8 v1 = *reinterpret_cast<const bf16x8*>(
                    vb + row * 128 + ((64 + lg * 16) ^ xorv));
                oacc[dt] = MFMA(ap0, v0, oacc[dt]);
                oacc[dt] = MFMA(ap1, v1, oacc[dt]);
            }
        }
        // H: convert staged saw+mask -> ebuf[nxt] (waits on B's loads via use-deps)
        WRITE_EBUF(nxt);
        // G: phase barrier (drains gload_lds vmcnt + all lgkm)
        __syncthreads();
        cur = nxt;
    }

    // rowsum reduce across the 16 lr lanes
#pragma unroll
    for (int r = 0; r < 4; ++r) {
        float s = rowsum[r];
#pragma unroll
        for (int m = 1; m < 16; m <<= 1) s += __shfl_xor(s, m);
        rowsum[r] = s;
    }
    float invden[4];
#pragma unroll
    for (int r = 0; r < 4; ++r) {
        const int srow = s0 + w * 16 + lg * 4 + r;
        invden[r] = 1.0f / (rowsum[r] + 1e-6f + __expf(lse[(size_t)bh * 1024 + srow]));
    }
#pragma unroll
    for (int dt = 0; dt < 8; ++dt) {
#pragma unroll
        for (int r = 0; r < 4; ++r) {
            const int srow = s0 + w * 16 + lg * 4 + r;
            out[((size_t)b * 1024 + srow) * 2048 + h * 128 + dt * 16 + lr] =
                oacc[dt][r] * invden[r];
        }
    }
#undef STAGE_VT
#undef LOAD_SAWM
#undef WRITE_EBUF
}

extern "C" void kernel_launch(void* const* d_in, const int* in_sizes, int n_in,
                              void* d_out, int out_size, void* d_ws, size_t ws_size,
                              hipStream_t stream)
{
    const float* q   = (const float*)d_in[0];
    const float* k   = (const float*)d_in[1];
    const float* v   = (const float*)d_in[2];
    const unsigned char* mask = (const unsigned char*)d_in[3];
    const float* lse = (const float*)d_in[4];
    const float* saw = (const float*)d_in[5];
    const float* wq1 = (const float*)d_in[6];
    const float* wk1 = (const float*)d_in[7];
    const float* wq2 = (const float*)d_in[8];
    const float* wk2 = (const float*)d_in[9];
    const float* iK  = (const float*)d_in[10];
    const float* sD  = (const float*)d_in[11];
    const float* sD2 = (const float*)d_in[12];
    float* out = (float*)d_out;

    bf16_t* wsb  = (bf16_t*)d_ws;
    bf16_t* wq1t = wsb;                    // 16*128*128 = 262144
    bf16_t* wk1t = wq1t + 262144;
    bf16_t* wq2t = wk1t + 262144;          // 16*64*128 = 131072
    bf16_t* wk2t = wq2t + 131072;
    bf16_t* iKt  = wk2t + 131072;          // 16*64*64  = 65536
    bf16_t* qf   = iKt  + 65536;           // 4*16*1024*64 = 4194304
    bf16_t* kf   = qf   + 4194304;
    bf16_t* vT   = kf   + 4194304;         // 4*16*128*1024 = 8388608 (tiled)
    // total ws use: ~35.3 MB

    conv_weights_kernel<<<dim3(1024), dim3(256), 0, stream>>>(
        wq1, wk1, wq2, wk2, iK, wq1t, wk1t, wq2t, wk2t, iKt);
    conv_v_kernel<<<dim3(64, 16), dim3(256), 0, stream>>>(v, vT);
    feat_kernel<<<dim3(64, 16, 2), dim3(256), 0, stream>>>(
        q, k, wq1t, wq2t, wk1t, wk2t, iKt, sD, sD2, qf, kf);
    attn_fused_kernel<<<dim3(16, 64), dim3(256), 0, stream>>>(
        qf, kf, vT, mask, saw, lse, out);
}